// Round 5
// baseline (267.597 us; speedup 1.0000x reference)
//
#include <hip/hip_runtime.h>

using u16 = unsigned short;
typedef __attribute__((ext_vector_type(8))) short short8;
typedef __attribute__((ext_vector_type(4))) float floatx4;

#define NQ 1024
#define NK 2048
#define DD 512

__device__ __forceinline__ u16 f2bf(float f) {
  union { float f; unsigned u; } x; x.f = f;
  unsigned r = (x.u + 0x7fffu + ((x.u >> 16) & 1u)) >> 16;
  return (u16)r;
}
__device__ __forceinline__ float bf2f(u16 u) {
  union { unsigned u; float f; } x; x.u = ((unsigned)u) << 16; return x.f;
}
__device__ __forceinline__ float wave_sum(float v) {
#pragma unroll
  for (int off = 32; off > 0; off >>= 1) v += __shfl_down(v, off, 64);
  return v;
}
__device__ __forceinline__ void gload16(const u16* g, const u16* l) {
  __builtin_amdgcn_global_load_lds(
      (const __attribute__((address_space(1))) void*)g,
      (__attribute__((address_space(3))) void*)l, 16, 0, 0);
}

// ------- fused: LN(inputs) + LN(context) + 3x weight cvt + zero Z/colV ------
__global__ __launch_bounds__(256) void ln_prep(
    const float* __restrict__ X1, const float* __restrict__ G1,
    const float* __restrict__ B1, u16* __restrict__ Y1,
    const float* __restrict__ X2, const float* __restrict__ G2,
    const float* __restrict__ B2, u16* __restrict__ Y2,
    const float* __restrict__ Wq, const float* __restrict__ Wk,
    const float* __restrict__ Wv, u16* __restrict__ wqb,
    u16* __restrict__ wkb, u16* __restrict__ wvb, float* __restrict__ Zero) {
  int row = blockIdx.x;
  const int t = threadIdx.x;
  if (row >= 24576) {
    int bx = row - 24576;
    if (bx < 768) {
      const float* src = bx < 256 ? Wq : (bx < 512 ? Wk : Wv);
      u16* dst = bx < 256 ? wqb : (bx < 512 ? wkb : wvb);
      int i = ((bx & 255) * 256 + t) * 4;
      float4 v = *(const float4*)(src + i);
      ushort4 o;
      o.x = f2bf(v.x); o.y = f2bf(v.y); o.z = f2bf(v.z); o.w = f2bf(v.w);
      *(ushort4*)(dst + i) = o;
    } else {
      int i = ((bx - 768) * 256 + t) * 4;
      float4 z = {0.f, 0.f, 0.f, 0.f};
      *(float4*)(Zero + i) = z;
    }
    return;
  }
  const float *X, *G, *Bv; u16* Y;
  if (row < 8192) { X = X1; G = G1; Bv = B1; Y = Y1; }
  else { row -= 8192; X = X2; G = G2; Bv = B2; Y = Y2; }
  const float2 v = ((const float2*)(X + (long)row * DD))[t];
  float s = v.x + v.y, ss = v.x * v.x + v.y * v.y;
  __shared__ float red[8];
  float a = wave_sum(s), b = wave_sum(ss);
  if ((t & 63) == 0) { red[t >> 6] = a; red[4 + (t >> 6)] = b; }
  __syncthreads();
  float tot = red[0] + red[1] + red[2] + red[3];
  float tss = red[4] + red[5] + red[6] + red[7];
  float mu = tot * (1.f / DD);
  float var = tss * (1.f / DD) - mu * mu;
  float rs = rsqrtf(var + 1e-5f);
  float2 g2 = ((const float2*)G)[t];
  float2 b2 = ((const float2*)Bv)[t];
  ushort2 o;
  o.x = f2bf((v.x - mu) * rs * g2.x + b2.x);
  o.y = f2bf((v.y - mu) * rs * g2.y + b2.y);
  ((ushort2*)(Y + (long)row * DD))[t] = o;
}

// ---------------- GEMM (B^T form): C[m,n] = sum_k A[m,k]*B[n,k] -------------
// epi 0: bf16 out, C = val + bias[n]  (2nd problem at blockIdx.x>=64 if A2)
// epi 3: QK: bf16 E = exp(val*scale); col sums atomicAdd -> aux0 (Z)
// epi 4: v-proj: val=acc+bias; bf16 val*rcp(Z) transposed [b][d][j];
//        unscaled col sums atomicAdd -> aux0 (colV); aux1 = Z
// Epilogue stages C in 32-row chunks through the 16KB K-loop LDS.
__global__ __launch_bounds__(256) void gemm_bt(
    const u16* A, const u16* B, const float* bias, void* Cout,
    const u16* A2, const u16* B2, const float* bias2, void* Cout2,
    int K, long sAb, long sBb, long sCb, int ldC,
    float scale, int epi, float* aux0, const float* aux1) {
  __shared__ u16 smem[8192];   // 16 KB: lA | lB, reused for epilogue staging
  __shared__ float colred[128];
  u16* lA = smem;
  u16* lB = smem + 4096;

  int m0 = blockIdx.x * 128;
  if (A2 != nullptr && blockIdx.x >= 64) {
    A = A2; B = B2; bias = bias2; Cout = Cout2;
    m0 = (blockIdx.x - 64) * 128;
  }
  const int bz = blockIdx.z;
  A += (long)bz * sAb;
  B += (long)bz * sBb;
  const int n0 = blockIdx.y * 128;
  const int t = threadIdx.x, wave = t >> 6, lane = t & 63;
  const int fm = lane & 15, fq = lane >> 4;
  const int wm = (wave >> 1) * 64, wn = (wave & 1) * 64;

  const u16* gA = A + (long)(m0 + wave * 16 + (lane >> 2)) * K + (lane & 3) * 8;
  const u16* gB = B + (long)(n0 + wave * 16 + (lane >> 2)) * K + (lane & 3) * 8;
  const long g64 = (long)64 * K;
  u16* lAw0 = lA + (wave * 16) * 32;
  u16* lAw1 = lA + (64 + wave * 16) * 32;
  u16* lBw0 = lB + (wave * 16) * 32;
  u16* lBw1 = lB + (64 + wave * 16) * 32;

  floatx4 acc[4][4];
#pragma unroll
  for (int x = 0; x < 4; ++x)
#pragma unroll
    for (int y = 0; y < 4; ++y) { floatx4 z = {0.f, 0.f, 0.f, 0.f}; acc[x][y] = z; }

  const int nkt = K >> 5;
  for (int kt = 0; kt < nkt; ++kt) {
    gload16(gA, lAw0);
    gload16(gA + g64, lAw1);
    gload16(gB, lBw0);
    gload16(gB + g64, lBw1);
    gA += 32; gB += 32;
    __syncthreads();
    short8 af[4], bfr[4];
#pragma unroll
    for (int x = 0; x < 4; ++x)
      af[x] = *(const short8*)&lA[(wm + x * 16 + fm) * 32 + fq * 8];
#pragma unroll
    for (int y = 0; y < 4; ++y)
      bfr[y] = *(const short8*)&lB[(wn + y * 16 + fm) * 32 + fq * 8];
#pragma unroll
    for (int x = 0; x < 4; ++x)
#pragma unroll
      for (int y = 0; y < 4; ++y)
        acc[x][y] = __builtin_amdgcn_mfma_f32_16x16x32_bf16(af[x], bfr[y], acc[x][y], 0, 0, 0);
    __syncthreads();
  }

  // ---------------- chunked epilogue (32 rows/chunk, 4 chunks) -----------
  float s4[4] = {0.f, 0.f, 0.f, 0.f};
  float bs[4];
  if (epi != 3) {
#pragma unroll
    for (int y = 0; y < 4; ++y) bs[y] = bias[n0 + wn + y * 16 + fm];
  }
  if ((epi == 3 || epi == 4) && t < 128) colred[t] = 0.f;
  const int bb = m0 >> 11;   // epi 4
  const int j0 = m0 & 2047;  // epi 4

  if (epi == 4) {
    float izv[16];
#pragma unroll
    for (int x = 0; x < 4; ++x)
#pragma unroll
      for (int r = 0; r < 4; ++r)
        izv[x * 4 + r] = __builtin_amdgcn_rcpf(
            aux1[bb * 2048 + j0 + wm + x * 16 + fq * 4 + r]);
    u16* Cg = (u16*)Cout + (long)bb * (512L * 2048) + j0;
#pragma unroll
    for (int c = 0; c < 4; ++c) {
      __syncthreads();
      if (wn == (c >> 1) * 64) {
#pragma unroll
        for (int yy = 0; yy < 2; ++yy) {
          int y = (c & 1) * 2 + yy;
          int ld = yy * 16 + fm;
#pragma unroll
          for (int x = 0; x < 4; ++x) {
            union { u16 q[4]; uint2 d; } pk;
#pragma unroll
            for (int r = 0; r < 4; ++r) {
              float val = acc[x][y][r] + bs[y];
              s4[y] += val;
              pk.q[r] = f2bf(val * izv[x * 4 + r]);
            }
            *(uint2*)&smem[ld * 136 + wm + x * 16 + fq * 4] = pk.d;
          }
        }
      }
      __syncthreads();
      int row = t >> 3, colc = (t & 7) * 16;
      short8 v0 = *(const short8*)&smem[row * 136 + colc];
      short8 v1 = *(const short8*)&smem[row * 136 + colc + 8];
      u16* og = Cg + (long)(n0 + c * 32 + row) * 2048 + colc;
      *(short8*)og = v0;
      *(short8*)(og + 8) = v1;
    }
  } else {
    u16* Cg = (u16*)Cout + (long)bz * sCb + n0;
#pragma unroll
    for (int c = 0; c < 4; ++c) {
      __syncthreads();
      if (wm == (c >> 1) * 64) {
#pragma unroll
        for (int xx = 0; xx < 2; ++xx) {
          int x = (c & 1) * 2 + xx;
#pragma unroll
          for (int y = 0; y < 4; ++y)
#pragma unroll
            for (int r = 0; r < 4; ++r) {
              float val = acc[x][y][r] * scale;
              if (epi == 0) val += bs[y];
              else { val = __expf(val); s4[y] += val; }
              int cl = (wn + y * 16 + fm) ^ (fq << 3);  // bank swizzle
              smem[(xx * 16 + fq * 4 + r) * 136 + cl] = f2bf(val);
            }
        }
      }
      __syncthreads();
      int row = t >> 3, colc = (t & 7) * 16;
      int sw = ((row >> 2) & 3) << 3;
      short8 v0 = *(const short8*)&smem[row * 136 + (colc ^ sw)];
      short8 v1 = *(const short8*)&smem[row * 136 + ((colc + 8) ^ sw)];
      u16* og = Cg + (long)(m0 + c * 32 + row) * ldC + colc;
      *(short8*)og = v0;
      *(short8*)(og + 8) = v1;
    }
  }

  if (epi == 3 || epi == 4) {
#pragma unroll
    for (int y = 0; y < 4; ++y) {
      s4[y] += __shfl_xor(s4[y], 16, 64);
      s4[y] += __shfl_xor(s4[y], 32, 64);
    }
    if (fq == 0) {
#pragma unroll
      for (int y = 0; y < 4; ++y) atomicAdd(&colred[wn + y * 16 + fm], s4[y]);
    }
    __syncthreads();
    if (epi == 3 && t < 128) atomicAdd(&aux0[bz * 2048 + n0 + t], colred[t]);
    if (epi == 4 && t < 128) atomicAdd(&aux0[bb * 512 + n0 + t], colred[t]);
  }
}

// ---------- R row-sums: invR[b][i] = 1/(sum_j E*rcp(Z) + NK*eps) ------------
__global__ __launch_bounds__(256) void rowsumR(const u16* __restrict__ E,
    const float* __restrict__ Z, float* __restrict__ invR) {
  const int row = blockIdx.x;
  const int b = row >> 10;
  const u16* p = E + (long)row * NK;
  const float* zp = Z + b * NK;
  const int t = threadIdx.x, j0 = t * 8;
  short8 v = *(const short8*)(p + j0);
  float4 z0 = *(const float4*)(zp + j0);
  float4 z1 = *(const float4*)(zp + j0 + 4);
  float sum = bf2f((u16)v[0]) * __builtin_amdgcn_rcpf(z0.x) +
              bf2f((u16)v[1]) * __builtin_amdgcn_rcpf(z0.y) +
              bf2f((u16)v[2]) * __builtin_amdgcn_rcpf(z0.z) +
              bf2f((u16)v[3]) * __builtin_amdgcn_rcpf(z0.w) +
              bf2f((u16)v[4]) * __builtin_amdgcn_rcpf(z1.x) +
              bf2f((u16)v[5]) * __builtin_amdgcn_rcpf(z1.y) +
              bf2f((u16)v[6]) * __builtin_amdgcn_rcpf(z1.z) +
              bf2f((u16)v[7]) * __builtin_amdgcn_rcpf(z1.w);
  __shared__ float red[4];
  float a = wave_sum(sum);
  if ((t & 63) == 0) red[t >> 6] = a;
  __syncthreads();
  if (t == 0) {
    float R = red[0] + red[1] + red[2] + red[3] + 2048.f * 1e-8f;
    invR[row] = 1.0f / R;
  }
}

// ------- PV: out[b][i][d] = (sum_j E[i,j]*vTs[d,j] + eps*colV[d]) * invR[i] --
// 64x128 tile, K=2048, chunked fp32 epilogue through 12KB K-loop LDS.
__global__ __launch_bounds__(256) void gemm_pv(const u16* __restrict__ E,
    const u16* __restrict__ V, const float* __restrict__ colV,
    const float* __restrict__ invR, float* __restrict__ out) {
  __shared__ u16 lds[6144];      // 12288 B
  u16* lA = lds;                 // 64 x 32
  u16* lB = lds + 2048;          // 128 x 32
  float* sO = (float*)lds;       // epilogue: 16 x 132 fp32 = 8448 B
  const int b = blockIdx.z;
  const int m0 = blockIdx.x * 64, n0 = blockIdx.y * 128;
  const int t = threadIdx.x, wave = t >> 6, lane = t & 63;
  const int fm = lane & 15, fq = lane >> 4;
  const int wml = (wave >> 1) * 32, wnl = (wave & 1) * 64;

  const u16* gA = E + (long)b * (1024L * 2048) +
                  (long)(m0 + wave * 16 + (lane >> 2)) * 2048 + (lane & 3) * 8;
  const u16* gB = V + (long)b * (512L * 2048) +
                  (long)(n0 + wave * 16 + (lane >> 2)) * 2048 + (lane & 3) * 8;
  u16* lAw = lA + (wave * 16) * 32;
  u16* lBw0 = lB + (wave * 16) * 32;
  u16* lBw1 = lB + (64 + wave * 16) * 32;

  floatx4 acc[2][4];
#pragma unroll
  for (int x = 0; x < 2; ++x)
#pragma unroll
    for (int y = 0; y < 4; ++y) { floatx4 z = {0.f, 0.f, 0.f, 0.f}; acc[x][y] = z; }

  for (int kt = 0; kt < 64; ++kt) {
    gload16(gA, lAw);
    gload16(gB, lBw0);
    gload16(gB + 64L * 2048, lBw1);
    gA += 32; gB += 32;
    __syncthreads();
    short8 af[2], bfr[4];
#pragma unroll
    for (int x = 0; x < 2; ++x)
      af[x] = *(const short8*)&lA[(wml + x * 16 + fm) * 32 + fq * 8];
#pragma unroll
    for (int y = 0; y < 4; ++y)
      bfr[y] = *(const short8*)&lB[(wnl + y * 16 + fm) * 32 + fq * 8];
#pragma unroll
    for (int x = 0; x < 2; ++x)
#pragma unroll
      for (int y = 0; y < 4; ++y)
        acc[x][y] = __builtin_amdgcn_mfma_f32_16x16x32_bf16(af[x], bfr[y], acc[x][y], 0, 0, 0);
    __syncthreads();
  }

  float cv[4], ir[8];
#pragma unroll
  for (int y = 0; y < 4; ++y) cv[y] = colV[b * 512 + n0 + wnl + y * 16 + fm];
#pragma unroll
  for (int x = 0; x < 2; ++x)
#pragma unroll
    for (int r = 0; r < 4; ++r)
      ir[x * 4 + r] = invR[b * 1024 + m0 + wml + x * 16 + fq * 4 + r];

  float* og = out + (long)b * (1024L * 512) + n0;
#pragma unroll
  for (int c = 0; c < 4; ++c) {
    __syncthreads();
    if (wml == (c >> 1) * 32) {
      int x = c & 1;
#pragma unroll
      for (int y = 0; y < 4; ++y)
#pragma unroll
        for (int r = 0; r < 4; ++r)
          sO[(fq * 4 + r) * 132 + wnl + y * 16 + fm] =
              (acc[x][y][r] + 1e-8f * cv[y]) * ir[x * 4 + r];
    }
    __syncthreads();
    int row = t >> 4, colc = (t & 15) * 8;
    float4 v0 = *(const float4*)&sO[row * 132 + colc];
    float4 v1 = *(const float4*)&sO[row * 132 + colc + 4];
    float* op = og + (long)(m0 + c * 16 + row) * 512 + colc;
    *(float4*)op = v0;
    *(float4*)(op + 4) = v1;
  }
}

extern "C" void kernel_launch(void* const* d_in, const int* in_sizes, int n_in,
                              void* d_out, int out_size, void* d_ws, size_t ws_size,
                              hipStream_t stream) {
  const float* inputs  = (const float*)d_in[0];
  const float* context = (const float*)d_in[1];
  const float* ln_in_g = (const float*)d_in[2];
  const float* ln_in_b = (const float*)d_in[3];
  const float* ln_ctx_g = (const float*)d_in[4];
  const float* ln_ctx_b = (const float*)d_in[5];
  const float* Wq = (const float*)d_in[6];
  const float* bq = (const float*)d_in[7];
  const float* Wk = (const float*)d_in[8];
  const float* bk = (const float*)d_in[9];
  const float* Wv = (const float*)d_in[10];
  const float* bv = (const float*)d_in[11];
  float* out = (float*)d_out;

  u16* ws = (u16*)d_ws;
  u16* xb  = ws;                        // [8192][512]
  u16* qb  = xb + 8192L * 512;          // [8192][512]
  u16* cb  = qb + 8192L * 512;          // [16384][512]
  u16* wqb = cb + 16384L * 512;         // [512][512]
  u16* wkb = wqb + 512L * 512;
  u16* wvb = wkb + 512L * 512;
  u16* kb  = wvb + 512L * 512;          // [16384][512]
  u16* vTs = kb + 16384L * 512;         // [8][512][2048] (v*rcp(Z), transposed)
  u16* E   = vTs + 8L * 512 * 2048;     // [8][1024][2048]
  float* Z    = (float*)(E + 8L * 1024 * 2048);   // [8][2048] raw col sums
  float* colV = Z + 8L * 2048;                    // [8][512]
  float* invR = colV + 8L * 512;                  // [8][1024]

  const float scale = 0.04419417382415922f;  // 512^-0.5

  // 1: LN(inputs)+LN(context) + weight cvt + zero Z/colV
  ln_prep<<<25364, 256, 0, stream>>>(inputs, ln_in_g, ln_in_b, xb,
                                     context, ln_ctx_g, ln_ctx_b, cb,
                                     Wq, Wk, Wv, wqb, wkb, wvb, Z);
  // 2: q-proj (bx<64) + k-proj (bx>=64), epi 0
  gemm_bt<<<dim3(192, 4, 1), 256, 0, stream>>>(xb, wqb, bq, qb,
      cb, wkb, bk, kb, 512, 0L, 0L, 0L, 512, 1.0f, 0, nullptr, nullptr);
  // 3: E = exp(q@k^T*scale), Z += col sums. epi 3
  gemm_bt<<<dim3(8, 16, 8), 256, 0, stream>>>(qb, kb, nullptr, E,
      nullptr, nullptr, nullptr, nullptr,
      512, 1024L * 512, 2048L * 512, 1024L * 2048, 2048, scale, 3, Z, nullptr);
  // 4: v-proj -> vTs (transposed, *rcp(Z)), colV += col sums. epi 4
  gemm_bt<<<dim3(128, 4, 1), 256, 0, stream>>>(cb, wvb, bv, vTs,
      nullptr, nullptr, nullptr, nullptr,
      512, 0L, 0L, 0L, 0, 1.0f, 4, colV, Z);
  // 5: invR
  rowsumR<<<8192, 256, 0, stream>>>(E, Z, invR);
  // 6: PV direct
  gemm_pv<<<dim3(16, 4, 8), 256, 0, stream>>>(E, vTs, colV, invR, out);
}

// Round 6
// 253.927 us; speedup vs baseline: 1.0538x; 1.0538x over previous
//
#include <hip/hip_runtime.h>

using u16 = unsigned short;
typedef __attribute__((ext_vector_type(8))) short short8;
typedef __attribute__((ext_vector_type(4))) float floatx4;

#define NQ 1024
#define NK 2048
#define DD 512

__device__ __forceinline__ u16 f2bf(float f) {
  union { float f; unsigned u; } x; x.f = f;
  unsigned r = (x.u + 0x7fffu + ((x.u >> 16) & 1u)) >> 16;
  return (u16)r;
}
__device__ __forceinline__ float bf2f(u16 u) {
  union { unsigned u; float f; } x; x.u = ((unsigned)u) << 16; return x.f;
}
__device__ __forceinline__ float wave_sum(float v) {
#pragma unroll
  for (int off = 32; off > 0; off >>= 1) v += __shfl_down(v, off, 64);
  return v;
}
__device__ __forceinline__ void gload16(const u16* g, const u16* l) {
  __builtin_amdgcn_global_load_lds(
      (const __attribute__((address_space(1))) void*)g,
      (__attribute__((address_space(3))) void*)l, 16, 0, 0);
}

// ------- fused: LN(inputs) + LN(context) + 3x weight cvt + zero Z/colV ------
__global__ __launch_bounds__(256) void ln_prep(
    const float* __restrict__ X1, const float* __restrict__ G1,
    const float* __restrict__ B1, u16* __restrict__ Y1,
    const float* __restrict__ X2, const float* __restrict__ G2,
    const float* __restrict__ B2, u16* __restrict__ Y2,
    const float* __restrict__ Wq, const float* __restrict__ Wk,
    const float* __restrict__ Wv, u16* __restrict__ wqb,
    u16* __restrict__ wkb, u16* __restrict__ wvb, float* __restrict__ Zero) {
  int row = blockIdx.x;
  const int t = threadIdx.x;
  if (row >= 24576) {
    int bx = row - 24576;
    if (bx < 768) {
      const float* src = bx < 256 ? Wq : (bx < 512 ? Wk : Wv);
      u16* dst = bx < 256 ? wqb : (bx < 512 ? wkb : wvb);
      int i = ((bx & 255) * 256 + t) * 4;
      float4 v = *(const float4*)(src + i);
      ushort4 o;
      o.x = f2bf(v.x); o.y = f2bf(v.y); o.z = f2bf(v.z); o.w = f2bf(v.w);
      *(ushort4*)(dst + i) = o;
    } else {
      int i = ((bx - 768) * 256 + t) * 4;
      float4 z = {0.f, 0.f, 0.f, 0.f};
      *(float4*)(Zero + i) = z;
    }
    return;
  }
  const float *X, *G, *Bv; u16* Y;
  if (row < 8192) { X = X1; G = G1; Bv = B1; Y = Y1; }
  else { row -= 8192; X = X2; G = G2; Bv = B2; Y = Y2; }
  const float2 v = ((const float2*)(X + (long)row * DD))[t];
  float s = v.x + v.y, ss = v.x * v.x + v.y * v.y;
  __shared__ float red[8];
  float a = wave_sum(s), b = wave_sum(ss);
  if ((t & 63) == 0) { red[t >> 6] = a; red[4 + (t >> 6)] = b; }
  __syncthreads();
  float tot = red[0] + red[1] + red[2] + red[3];
  float tss = red[4] + red[5] + red[6] + red[7];
  float mu = tot * (1.f / DD);
  float var = tss * (1.f / DD) - mu * mu;
  float rs = rsqrtf(var + 1e-5f);
  float2 g2 = ((const float2*)G)[t];
  float2 b2 = ((const float2*)Bv)[t];
  ushort2 o;
  o.x = f2bf((v.x - mu) * rs * g2.x + b2.x);
  o.y = f2bf((v.y - mu) * rs * g2.y + b2.y);
  ((ushort2*)(Y + (long)row * DD))[t] = o;
}

// ---------------- GEMM (B^T form): C[m,n] = sum_k A[m,k]*B[n,k] -------------
// epi 0: bf16 out, C = val + bias[n]  (2nd problem at blockIdx.x>=64 if A2)
// epi 3: QK: batch = blockIdx.x (XCD locality), m0 = blockIdx.z*128.
//        bf16 E = exp(val*scale); col sums atomicAdd -> aux0 (Z)
// epi 6: v-projT: A=Wv (M=512 d-rows), B=cb (N=16384 j-rows).
//        batch = n0>>11. bf16 vT[b][d][j] = (val + bias[d]) * rcp(Z[b][j]);
//        row sums (over j) of unscaled val atomicAdd -> aux0 (colV[b][d]).
__global__ __launch_bounds__(256) void gemm_bt(
    const u16* A, const u16* B, const float* bias, void* Cout,
    const u16* A2, const u16* B2, const float* bias2, void* Cout2,
    int K, long sAb, long sBb, long sCb, int ldC,
    float scale, int epi, float* aux0, const float* aux1) {
  __shared__ u16 lA[128 * 32];
  __shared__ u16 lB[128 * 32];
  __shared__ float colred[128];

  int m0, n0, bz;
  if (epi == 3) {
    bz = blockIdx.x; m0 = blockIdx.z * 128; n0 = blockIdx.y * 128;
  } else {
    bz = blockIdx.z; m0 = blockIdx.x * 128; n0 = blockIdx.y * 128;
    if (A2 != nullptr && blockIdx.x >= 64) {
      A = A2; B = B2; bias = bias2; Cout = Cout2;
      m0 = (blockIdx.x - 64) * 128;
    }
  }
  A += (long)bz * sAb;
  B += (long)bz * sBb;
  const int t = threadIdx.x, wave = t >> 6, lane = t & 63;
  const int fm = lane & 15, fq = lane >> 4;
  const int wm = (wave >> 1) * 64, wn = (wave & 1) * 64;

  const u16* gA = A + (long)(m0 + wave * 16 + (lane >> 2)) * K + (lane & 3) * 8;
  const u16* gB = B + (long)(n0 + wave * 16 + (lane >> 2)) * K + (lane & 3) * 8;
  const long g64 = (long)64 * K;
  u16* lAw0 = lA + (wave * 16) * 32;
  u16* lAw1 = lA + (64 + wave * 16) * 32;
  u16* lBw0 = lB + (wave * 16) * 32;
  u16* lBw1 = lB + (64 + wave * 16) * 32;

  floatx4 acc[4][4];
#pragma unroll
  for (int x = 0; x < 4; ++x)
#pragma unroll
    for (int y = 0; y < 4; ++y) { floatx4 z = {0.f, 0.f, 0.f, 0.f}; acc[x][y] = z; }

  const int nkt = K >> 5;
  for (int kt = 0; kt < nkt; ++kt) {
    gload16(gA, lAw0);
    gload16(gA + g64, lAw1);
    gload16(gB, lBw0);
    gload16(gB + g64, lBw1);
    gA += 32; gB += 32;
    __syncthreads();
    short8 af[4], bfr[4];
#pragma unroll
    for (int x = 0; x < 4; ++x)
      af[x] = *(const short8*)&lA[(wm + x * 16 + fm) * 32 + fq * 8];
#pragma unroll
    for (int y = 0; y < 4; ++y)
      bfr[y] = *(const short8*)&lB[(wn + y * 16 + fm) * 32 + fq * 8];
#pragma unroll
    for (int x = 0; x < 4; ++x)
#pragma unroll
      for (int y = 0; y < 4; ++y)
        acc[x][y] = __builtin_amdgcn_mfma_f32_16x16x32_bf16(af[x], bfr[y], acc[x][y], 0, 0, 0);
    __syncthreads();
  }

  if (epi == 0) {
    float bs[4];
#pragma unroll
    for (int y = 0; y < 4; ++y) bs[y] = bias[n0 + wn + y * 16 + fm];
#pragma unroll
    for (int x = 0; x < 4; ++x)
#pragma unroll
      for (int y = 0; y < 4; ++y)
#pragma unroll
        for (int r = 0; r < 4; ++r) {
          int row = m0 + wm + x * 16 + fq * 4 + r;
          int col = n0 + wn + y * 16 + fm;
          ((u16*)Cout)[(long)bz * sCb + (long)row * ldC + col] =
              f2bf(acc[x][y][r] + bs[y]);
        }
  } else if (epi == 3) {
    float s4[4] = {0.f, 0.f, 0.f, 0.f};
#pragma unroll
    for (int x = 0; x < 4; ++x)
#pragma unroll
      for (int y = 0; y < 4; ++y)
#pragma unroll
        for (int r = 0; r < 4; ++r) {
          int row = m0 + wm + x * 16 + fq * 4 + r;
          int col = n0 + wn + y * 16 + fm;
          float e = __expf(acc[x][y][r] * scale);
          s4[y] += e;
          ((u16*)Cout)[(long)bz * sCb + (long)row * ldC + col] = f2bf(e);
        }
#pragma unroll
    for (int y = 0; y < 4; ++y) {
      s4[y] += __shfl_xor(s4[y], 16, 64);
      s4[y] += __shfl_xor(s4[y], 32, 64);
    }
    if (t < 128) colred[t] = 0.f;
    __syncthreads();
    if (fq == 0) {
#pragma unroll
      for (int y = 0; y < 4; ++y) atomicAdd(&colred[wn + y * 16 + fm], s4[y]);
    }
    __syncthreads();
    if (t < 128) atomicAdd(&aux0[bz * 2048 + n0 + t], colred[t]);
  } else {  // epi 6: v-projT
    const int bb = n0 >> 11;
    const int j0c = n0 & 2047;
    float bsr[4][4];
#pragma unroll
    for (int x = 0; x < 4; ++x)
#pragma unroll
      for (int r = 0; r < 4; ++r)
        bsr[x][r] = bias[m0 + wm + x * 16 + fq * 4 + r];
    float izv[4];
#pragma unroll
    for (int y = 0; y < 4; ++y)
      izv[y] = __builtin_amdgcn_rcpf(aux1[bb * 2048 + j0c + wn + y * 16 + fm]);
    u16* Cg = (u16*)Cout + (long)bb * (512L * 2048) + j0c;
    float rs[4][4];
#pragma unroll
    for (int x = 0; x < 4; ++x)
#pragma unroll
      for (int r = 0; r < 4; ++r) rs[x][r] = 0.f;
#pragma unroll
    for (int x = 0; x < 4; ++x)
#pragma unroll
      for (int y = 0; y < 4; ++y)
#pragma unroll
        for (int r = 0; r < 4; ++r) {
          int rowd = m0 + wm + x * 16 + fq * 4 + r;
          int col = wn + y * 16 + fm;
          float val = acc[x][y][r] + bsr[x][r];
          rs[x][r] += val;
          Cg[(long)rowd * 2048 + col] = f2bf(val * izv[y]);
        }
    // reduce row sums across the 16 fm lanes, then one atomic per row
#pragma unroll
    for (int x = 0; x < 4; ++x)
#pragma unroll
      for (int r = 0; r < 4; ++r) {
        float s = rs[x][r];
        s += __shfl_xor(s, 1, 64);
        s += __shfl_xor(s, 2, 64);
        s += __shfl_xor(s, 4, 64);
        s += __shfl_xor(s, 8, 64);
        if (fm == 0)
          atomicAdd(&aux0[bb * 512 + m0 + wm + x * 16 + fq * 4 + r], s);
      }
  }
}

// ---------- R row-sums: invR[b][i] = 1/(sum_j E*rcp(Z) + NK*eps) ------------
__global__ __launch_bounds__(256) void rowsumR(const u16* __restrict__ E,
    const float* __restrict__ Z, float* __restrict__ invR) {
  const int row = blockIdx.x;
  const int b = row >> 10;
  const u16* p = E + (long)row * NK;
  const float* zp = Z + b * NK;
  const int t = threadIdx.x, j0 = t * 8;
  short8 v = *(const short8*)(p + j0);
  float4 z0 = *(const float4*)(zp + j0);
  float4 z1 = *(const float4*)(zp + j0 + 4);
  float sum = bf2f((u16)v[0]) * __builtin_amdgcn_rcpf(z0.x) +
              bf2f((u16)v[1]) * __builtin_amdgcn_rcpf(z0.y) +
              bf2f((u16)v[2]) * __builtin_amdgcn_rcpf(z0.z) +
              bf2f((u16)v[3]) * __builtin_amdgcn_rcpf(z0.w) +
              bf2f((u16)v[4]) * __builtin_amdgcn_rcpf(z1.x) +
              bf2f((u16)v[5]) * __builtin_amdgcn_rcpf(z1.y) +
              bf2f((u16)v[6]) * __builtin_amdgcn_rcpf(z1.z) +
              bf2f((u16)v[7]) * __builtin_amdgcn_rcpf(z1.w);
  __shared__ float red[4];
  float a = wave_sum(sum);
  if ((t & 63) == 0) red[t >> 6] = a;
  __syncthreads();
  if (t == 0) {
    float R = red[0] + red[1] + red[2] + red[3] + 2048.f * 1e-8f;
    invR[row] = 1.0f / R;
  }
}

// ------- PV: out[b][i][d] = (sum_j E[i,j]*vT[d,j] + eps*colV[d]) * invR[i] --
__global__ __launch_bounds__(256) void gemm_pv(const u16* __restrict__ E,
    const u16* __restrict__ V, const float* __restrict__ colV,
    const float* __restrict__ invR, float* __restrict__ out) {
  __shared__ u16 lds[6144];      // 12288 B
  u16* lA = lds;                 // 64 x 32
  u16* lB = lds + 2048;          // 128 x 32
  float* sO = (float*)lds;       // epilogue: 16 x 132 fp32
  const int b = blockIdx.z;
  const int m0 = blockIdx.x * 64, n0 = blockIdx.y * 128;
  const int t = threadIdx.x, wave = t >> 6, lane = t & 63;
  const int fm = lane & 15, fq = lane >> 4;
  const int wml = (wave >> 1) * 32, wnl = (wave & 1) * 64;

  const u16* gA = E + (long)b * (1024L * 2048) +
                  (long)(m0 + wave * 16 + (lane >> 2)) * 2048 + (lane & 3) * 8;
  const u16* gB = V + (long)b * (512L * 2048) +
                  (long)(n0 + wave * 16 + (lane >> 2)) * 2048 + (lane & 3) * 8;
  u16* lAw = lA + (wave * 16) * 32;
  u16* lBw0 = lB + (wave * 16) * 32;
  u16* lBw1 = lB + (64 + wave * 16) * 32;

  floatx4 acc[2][4];
#pragma unroll
  for (int x = 0; x < 2; ++x)
#pragma unroll
    for (int y = 0; y < 4; ++y) { floatx4 z = {0.f, 0.f, 0.f, 0.f}; acc[x][y] = z; }

  for (int kt = 0; kt < 64; ++kt) {
    gload16(gA, lAw);
    gload16(gB, lBw0);
    gload16(gB + 64L * 2048, lBw1);
    gA += 32; gB += 32;
    __syncthreads();
    short8 af[2], bfr[4];
#pragma unroll
    for (int x = 0; x < 2; ++x)
      af[x] = *(const short8*)&lA[(wml + x * 16 + fm) * 32 + fq * 8];
#pragma unroll
    for (int y = 0; y < 4; ++y)
      bfr[y] = *(const short8*)&lB[(wnl + y * 16 + fm) * 32 + fq * 8];
#pragma unroll
    for (int x = 0; x < 2; ++x)
#pragma unroll
      for (int y = 0; y < 4; ++y)
        acc[x][y] = __builtin_amdgcn_mfma_f32_16x16x32_bf16(af[x], bfr[y], acc[x][y], 0, 0, 0);
    __syncthreads();
  }

  float cv[4], ir[8];
#pragma unroll
  for (int y = 0; y < 4; ++y) cv[y] = colV[b * 512 + n0 + wnl + y * 16 + fm];
#pragma unroll
  for (int x = 0; x < 2; ++x)
#pragma unroll
    for (int r = 0; r < 4; ++r)
      ir[x * 4 + r] = invR[b * 1024 + m0 + wml + x * 16 + fq * 4 + r];

  float* og = out + (long)b * (1024L * 512) + n0;
#pragma unroll
  for (int c = 0; c < 4; ++c) {
    __syncthreads();
    if (wml == (c >> 1) * 32) {
      int x = c & 1;
#pragma unroll
      for (int y = 0; y < 4; ++y)
#pragma unroll
        for (int r = 0; r < 4; ++r)
          sO[(fq * 4 + r) * 132 + wnl + y * 16 + fm] =
              (acc[x][y][r] + 1e-8f * cv[y]) * ir[x * 4 + r];
    }
    __syncthreads();
    int row = t >> 4, colc = (t & 15) * 8;
    float4 v0 = *(const float4*)&sO[row * 132 + colc];
    float4 v1 = *(const float4*)&sO[row * 132 + colc + 4];
    float* op = og + (long)(m0 + c * 16 + row) * 512 + colc;
    *(float4*)op = v0;
    *(float4*)(op + 4) = v1;
  }
}

extern "C" void kernel_launch(void* const* d_in, const int* in_sizes, int n_in,
                              void* d_out, int out_size, void* d_ws, size_t ws_size,
                              hipStream_t stream) {
  const float* inputs  = (const float*)d_in[0];
  const float* context = (const float*)d_in[1];
  const float* ln_in_g = (const float*)d_in[2];
  const float* ln_in_b = (const float*)d_in[3];
  const float* ln_ctx_g = (const float*)d_in[4];
  const float* ln_ctx_b = (const float*)d_in[5];
  const float* Wq = (const float*)d_in[6];
  const float* bq = (const float*)d_in[7];
  const float* Wk = (const float*)d_in[8];
  const float* bk = (const float*)d_in[9];
  const float* Wv = (const float*)d_in[10];
  const float* bv = (const float*)d_in[11];
  float* out = (float*)d_out;

  u16* ws = (u16*)d_ws;
  u16* xb  = ws;                        // [8192][512]
  u16* qb  = xb + 8192L * 512;          // [8192][512]
  u16* cb  = qb + 8192L * 512;          // [16384][512]
  u16* wqb = cb + 16384L * 512;         // [512][512]
  u16* wkb = wqb + 512L * 512;
  u16* wvb = wkb + 512L * 512;
  u16* kb  = wvb + 512L * 512;          // [16384][512]
  u16* vTs = kb + 16384L * 512;         // [8][512][2048] (v*rcp(Z), transposed)
  u16* E   = vTs + 8L * 512 * 2048;     // [8][1024][2048]
  float* Z    = (float*)(E + 8L * 1024 * 2048);   // [8][2048] raw col sums
  float* colV = Z + 8L * 2048;                    // [8][512]
  float* invR = colV + 8L * 512;                  // [8][1024]

  const float scale = 0.04419417382415922f;  // 512^-0.5

  // 1: LN(inputs)+LN(context) + weight cvt + zero Z/colV
  ln_prep<<<25364, 256, 0, stream>>>(inputs, ln_in_g, ln_in_b, xb,
                                     context, ln_ctx_g, ln_ctx_b, cb,
                                     Wq, Wk, Wv, wqb, wkb, wvb, Z);
  // 2: q-proj (bx<64) + k-proj (bx>=64), epi 0
  gemm_bt<<<dim3(192, 4, 1), 256, 0, stream>>>(xb, wqb, bq, qb,
      cb, wkb, bk, kb, 512, 0L, 0L, 0L, 512, 1.0f, 0, nullptr, nullptr);
  // 3: E = exp(q@k^T*scale), Z += col sums. epi 3, batch on blockIdx.x (XCD)
  gemm_bt<<<dim3(8, 16, 8), 256, 0, stream>>>(qb, kb, nullptr, E,
      nullptr, nullptr, nullptr, nullptr,
      512, 1024L * 512, 2048L * 512, 1024L * 2048, 2048, scale, 3, Z, nullptr);
  // 4: v-projT: vT[b][d][j] = (Wv[d]·cb[j] + bv[d])*rcp(Z), colV += row sums
  gemm_bt<<<dim3(4, 128, 1), 256, 0, stream>>>(wvb, cb, bv, vTs,
      nullptr, nullptr, nullptr, nullptr,
      512, 0L, 0L, 0L, 2048, 1.0f, 6, colV, Z);
  // 5: invR
  rowsumR<<<8192, 256, 0, stream>>>(E, Z, invR);
  // 6: PV direct
  gemm_pv<<<dim3(16, 4, 8), 256, 0, stream>>>(E, vTs, colV, invR, out);
}

// Round 7
// 230.458 us; speedup vs baseline: 1.1612x; 1.1018x over previous
//
#include <hip/hip_runtime.h>

using u16 = unsigned short;
typedef __attribute__((ext_vector_type(8))) short short8;
typedef __attribute__((ext_vector_type(4))) float floatx4;

#define NQ 1024
#define NK 2048
#define DD 512

__device__ __forceinline__ u16 f2bf(float f) {
  union { float f; unsigned u; } x; x.f = f;
  unsigned r = (x.u + 0x7fffu + ((x.u >> 16) & 1u)) >> 16;
  return (u16)r;
}
__device__ __forceinline__ float bf2f(u16 u) {
  union { unsigned u; float f; } x; x.u = ((unsigned)u) << 16; return x.f;
}
__device__ __forceinline__ float wave_sum(float v) {
#pragma unroll
  for (int off = 32; off > 0; off >>= 1) v += __shfl_down(v, off, 64);
  return v;
}
__device__ __forceinline__ void gload16(const u16* g, const u16* l) {
  __builtin_amdgcn_global_load_lds(
      (const __attribute__((address_space(1))) void*)g,
      (__attribute__((address_space(3))) void*)l, 16, 0, 0);
}

// ------- fused: LN(inputs) + LN(context) + 3x weight cvt + zero Z/colV ------
__global__ __launch_bounds__(256) void ln_prep(
    const float* __restrict__ X1, const float* __restrict__ G1,
    const float* __restrict__ B1, u16* __restrict__ Y1,
    const float* __restrict__ X2, const float* __restrict__ G2,
    const float* __restrict__ B2, u16* __restrict__ Y2,
    const float* __restrict__ Wq, const float* __restrict__ Wk,
    const float* __restrict__ Wv, u16* __restrict__ wqb,
    u16* __restrict__ wkb, u16* __restrict__ wvb, float* __restrict__ Zero) {
  int row = blockIdx.x;
  const int t = threadIdx.x;
  if (row >= 24576) {
    int bx = row - 24576;
    if (bx < 768) {
      const float* src = bx < 256 ? Wq : (bx < 512 ? Wk : Wv);
      u16* dst = bx < 256 ? wqb : (bx < 512 ? wkb : wvb);
      int i = ((bx & 255) * 256 + t) * 4;
      float4 v = *(const float4*)(src + i);
      ushort4 o;
      o.x = f2bf(v.x); o.y = f2bf(v.y); o.z = f2bf(v.z); o.w = f2bf(v.w);
      *(ushort4*)(dst + i) = o;
    } else {
      int i = ((bx - 768) * 256 + t) * 4;
      float4 z = {0.f, 0.f, 0.f, 0.f};
      *(float4*)(Zero + i) = z;
    }
    return;
  }
  const float *X, *G, *Bv; u16* Y;
  if (row < 8192) { X = X1; G = G1; Bv = B1; Y = Y1; }
  else { row -= 8192; X = X2; G = G2; Bv = B2; Y = Y2; }
  const float2 v = ((const float2*)(X + (long)row * DD))[t];
  float s = v.x + v.y, ss = v.x * v.x + v.y * v.y;
  __shared__ float red[8];
  float a = wave_sum(s), b = wave_sum(ss);
  if ((t & 63) == 0) { red[t >> 6] = a; red[4 + (t >> 6)] = b; }
  __syncthreads();
  float tot = red[0] + red[1] + red[2] + red[3];
  float tss = red[4] + red[5] + red[6] + red[7];
  float mu = tot * (1.f / DD);
  float var = tss * (1.f / DD) - mu * mu;
  float rs = rsqrtf(var + 1e-5f);
  float2 g2 = ((const float2*)G)[t];
  float2 b2 = ((const float2*)Bv)[t];
  ushort2 o;
  o.x = f2bf((v.x - mu) * rs * g2.x + b2.x);
  o.y = f2bf((v.y - mu) * rs * g2.y + b2.y);
  ((ushort2*)(Y + (long)row * DD))[t] = o;
}

// ------------- GEMM (B^T form), BK=64, swizzled LDS: C = A·B^T --------------
// epi 0: bf16 out, C = val + bias[n]  (2nd problem at blockIdx.x>=64 if A2)
// epi 3: QK: batch = blockIdx.x, m0 = blockIdx.z*128.
//        bf16 E = exp(val*scale); col sums atomicAdd -> aux0 (Z)
// epi 6: v-projT: A=Wv, B=cb. bf16 vT[b][d][j] = (val+bias[d])*rcp(Z[b][j]);
//        row sums of unscaled val atomicAdd -> aux0 (colV[b][d])
__global__ __launch_bounds__(256) void gemm_bt(
    const u16* A, const u16* B, const float* bias, void* Cout,
    const u16* A2, const u16* B2, const float* bias2, void* Cout2,
    int K, long sAb, long sBb, long sCb, int ldC,
    float scale, int epi, float* aux0, const float* aux1) {
  __shared__ u16 lA[128 * 64];
  __shared__ u16 lB[128 * 64];
  __shared__ float colred[128];

  int m0, n0, bz;
  if (epi == 3) {
    bz = blockIdx.x; m0 = blockIdx.z * 128; n0 = blockIdx.y * 128;
  } else {
    bz = blockIdx.z; m0 = blockIdx.x * 128; n0 = blockIdx.y * 128;
    if (A2 != nullptr && blockIdx.x >= 64) {
      A = A2; B = B2; bias = bias2; Cout = Cout2;
      m0 = (blockIdx.x - 64) * 128;
    }
  }
  A += (long)bz * sAb;
  B += (long)bz * sBb;
  const int t = threadIdx.x, wave = t >> 6, lane = t & 63;
  const int fm = lane & 15, fq = lane >> 4;
  const int wm = (wave >> 1) * 64, wn = (wave & 1) * 64;

  // staging: thread covers row (i*32 + t>>3), global chunk (t&7)^(row&7)
  const int srow = t >> 3;
  const int swz = ((t & 7) ^ (srow & 7)) * 8;
  const u16* gA = A + (long)(m0 + srow) * K + swz;
  const u16* gB = B + (long)(n0 + srow) * K + swz;
  const long gk32 = 32L * K;
  u16* dA = lA + wave * 512;
  u16* dB = lB + wave * 512;

  floatx4 acc[4][4];
#pragma unroll
  for (int x = 0; x < 4; ++x)
#pragma unroll
    for (int y = 0; y < 4; ++y) { floatx4 z = {0.f, 0.f, 0.f, 0.f}; acc[x][y] = z; }

  const int nkt = K >> 6;
  for (int kt = 0; kt < nkt; ++kt) {
    gload16(gA, dA);
    gload16(gA + gk32, dA + 2048);
    gload16(gA + 2 * gk32, dA + 4096);
    gload16(gA + 3 * gk32, dA + 6144);
    gload16(gB, dB);
    gload16(gB + gk32, dB + 2048);
    gload16(gB + 2 * gk32, dB + 4096);
    gload16(gB + 3 * gk32, dB + 6144);
    gA += 64; gB += 64;
    __syncthreads();
#pragma unroll
    for (int ks = 0; ks < 2; ++ks) {
      short8 af[4], bfr[4];
      const int csl = ((ks * 4 + fq) ^ (fm & 7)) * 8;
#pragma unroll
      for (int x = 0; x < 4; ++x)
        af[x] = *(const short8*)&lA[(wm + x * 16 + fm) * 64 + csl];
#pragma unroll
      for (int y = 0; y < 4; ++y)
        bfr[y] = *(const short8*)&lB[(wn + y * 16 + fm) * 64 + csl];
#pragma unroll
      for (int x = 0; x < 4; ++x)
#pragma unroll
        for (int y = 0; y < 4; ++y)
          acc[x][y] = __builtin_amdgcn_mfma_f32_16x16x32_bf16(af[x], bfr[y], acc[x][y], 0, 0, 0);
    }
    __syncthreads();
  }

  if (epi == 0) {
    float bs[4];
#pragma unroll
    for (int y = 0; y < 4; ++y) bs[y] = bias[n0 + wn + y * 16 + fm];
#pragma unroll
    for (int x = 0; x < 4; ++x)
#pragma unroll
      for (int y = 0; y < 4; ++y)
#pragma unroll
        for (int r = 0; r < 4; ++r) {
          int row = m0 + wm + x * 16 + fq * 4 + r;
          int col = n0 + wn + y * 16 + fm;
          ((u16*)Cout)[(long)bz * sCb + (long)row * ldC + col] =
              f2bf(acc[x][y][r] + bs[y]);
        }
  } else if (epi == 3) {
    float s4[4] = {0.f, 0.f, 0.f, 0.f};
#pragma unroll
    for (int x = 0; x < 4; ++x)
#pragma unroll
      for (int y = 0; y < 4; ++y)
#pragma unroll
        for (int r = 0; r < 4; ++r) {
          int row = m0 + wm + x * 16 + fq * 4 + r;
          int col = n0 + wn + y * 16 + fm;
          float e = __expf(acc[x][y][r] * scale);
          s4[y] += e;
          ((u16*)Cout)[(long)bz * sCb + (long)row * ldC + col] = f2bf(e);
        }
#pragma unroll
    for (int y = 0; y < 4; ++y) {
      s4[y] += __shfl_xor(s4[y], 16, 64);
      s4[y] += __shfl_xor(s4[y], 32, 64);
    }
    if (t < 128) colred[t] = 0.f;
    __syncthreads();
    if (fq == 0) {
#pragma unroll
      for (int y = 0; y < 4; ++y) atomicAdd(&colred[wn + y * 16 + fm], s4[y]);
    }
    __syncthreads();
    if (t < 128) atomicAdd(&aux0[bz * 2048 + n0 + t], colred[t]);
  } else {  // epi 6: v-projT
    const int bb = n0 >> 11;
    const int j0c = n0 & 2047;
    float bsr[4][4];
#pragma unroll
    for (int x = 0; x < 4; ++x)
#pragma unroll
      for (int r = 0; r < 4; ++r)
        bsr[x][r] = bias[m0 + wm + x * 16 + fq * 4 + r];
    float izv[4];
#pragma unroll
    for (int y = 0; y < 4; ++y)
      izv[y] = __builtin_amdgcn_rcpf(aux1[bb * 2048 + j0c + wn + y * 16 + fm]);
    u16* Cg = (u16*)Cout + (long)bb * (512L * 2048) + j0c;
    float rs[4][4];
#pragma unroll
    for (int x = 0; x < 4; ++x)
#pragma unroll
      for (int r = 0; r < 4; ++r) rs[x][r] = 0.f;
#pragma unroll
    for (int x = 0; x < 4; ++x)
#pragma unroll
      for (int y = 0; y < 4; ++y)
#pragma unroll
        for (int r = 0; r < 4; ++r) {
          int rowd = m0 + wm + x * 16 + fq * 4 + r;
          int col = wn + y * 16 + fm;
          float val = acc[x][y][r] + bsr[x][r];
          rs[x][r] += val;
          Cg[(long)rowd * 2048 + col] = f2bf(val * izv[y]);
        }
#pragma unroll
    for (int x = 0; x < 4; ++x)
#pragma unroll
      for (int r = 0; r < 4; ++r) {
        float s = rs[x][r];
        s += __shfl_xor(s, 1, 64);
        s += __shfl_xor(s, 2, 64);
        s += __shfl_xor(s, 4, 64);
        s += __shfl_xor(s, 8, 64);
        if (fm == 0)
          atomicAdd(&aux0[bb * 512 + m0 + wm + x * 16 + fq * 4 + r], s);
      }
  }
}

// ---------- R row-sums: invR[b][i] = 1/(sum_j E*rcp(Z) + NK*eps) ------------
__global__ __launch_bounds__(256) void rowsumR(const u16* __restrict__ E,
    const float* __restrict__ Z, float* __restrict__ invR) {
  const int row = blockIdx.x;
  const int b = row >> 10;
  const u16* p = E + (long)row * NK;
  const float* zp = Z + b * NK;
  const int t = threadIdx.x, j0 = t * 8;
  short8 v = *(const short8*)(p + j0);
  float4 z0 = *(const float4*)(zp + j0);
  float4 z1 = *(const float4*)(zp + j0 + 4);
  float sum = bf2f((u16)v[0]) * __builtin_amdgcn_rcpf(z0.x) +
              bf2f((u16)v[1]) * __builtin_amdgcn_rcpf(z0.y) +
              bf2f((u16)v[2]) * __builtin_amdgcn_rcpf(z0.z) +
              bf2f((u16)v[3]) * __builtin_amdgcn_rcpf(z0.w) +
              bf2f((u16)v[4]) * __builtin_amdgcn_rcpf(z1.x) +
              bf2f((u16)v[5]) * __builtin_amdgcn_rcpf(z1.y) +
              bf2f((u16)v[6]) * __builtin_amdgcn_rcpf(z1.z) +
              bf2f((u16)v[7]) * __builtin_amdgcn_rcpf(z1.w);
  __shared__ float red[4];
  float a = wave_sum(sum);
  if ((t & 63) == 0) red[t >> 6] = a;
  __syncthreads();
  if (t == 0) {
    float R = red[0] + red[1] + red[2] + red[3] + 2048.f * 1e-8f;
    invR[row] = 1.0f / R;
  }
}

// ------- PV: out[b][i][d] = (sum_j E[i,j]*vT[d,j] + eps*colV[d]) * invR[i] --
// 64x64 tile, BK=64, grid (16,8,8)=1024 -> 4 blocks/CU.
__global__ __launch_bounds__(256) void gemm_pv(const u16* __restrict__ E,
    const u16* __restrict__ V, const float* __restrict__ colV,
    const float* __restrict__ invR, float* __restrict__ out) {
  __shared__ u16 lA[64 * 64];
  __shared__ u16 lB[64 * 64];
  const int b = blockIdx.z;
  const int m0 = blockIdx.x * 64, n0 = blockIdx.y * 64;
  const int t = threadIdx.x, wave = t >> 6, lane = t & 63;
  const int fm = lane & 15, fq = lane >> 4;
  const int wm = (wave >> 1) * 32, wn = (wave & 1) * 32;

  const int srow = t >> 3;
  const int swz = ((t & 7) ^ (srow & 7)) * 8;
  const u16* gA = E + (long)b * (1024L * 2048) + (long)(m0 + srow) * 2048 + swz;
  const u16* gB = V + (long)b * (512L * 2048) + (long)(n0 + srow) * 2048 + swz;
  u16* dA = lA + wave * 512;
  u16* dB = lB + wave * 512;

  floatx4 acc[2][2];
#pragma unroll
  for (int x = 0; x < 2; ++x)
#pragma unroll
    for (int y = 0; y < 2; ++y) { floatx4 z = {0.f, 0.f, 0.f, 0.f}; acc[x][y] = z; }

  for (int kt = 0; kt < 32; ++kt) {
    gload16(gA, dA);
    gload16(gA + 32L * 2048, dA + 2048);
    gload16(gB, dB);
    gload16(gB + 32L * 2048, dB + 2048);
    gA += 64; gB += 64;
    __syncthreads();
#pragma unroll
    for (int ks = 0; ks < 2; ++ks) {
      short8 af[2], bfr[2];
      const int csl = ((ks * 4 + fq) ^ (fm & 7)) * 8;
#pragma unroll
      for (int x = 0; x < 2; ++x)
        af[x] = *(const short8*)&lA[(wm + x * 16 + fm) * 64 + csl];
#pragma unroll
      for (int y = 0; y < 2; ++y)
        bfr[y] = *(const short8*)&lB[(wn + y * 16 + fm) * 64 + csl];
#pragma unroll
      for (int x = 0; x < 2; ++x)
#pragma unroll
        for (int y = 0; y < 2; ++y)
          acc[x][y] = __builtin_amdgcn_mfma_f32_16x16x32_bf16(af[x], bfr[y], acc[x][y], 0, 0, 0);
    }
    __syncthreads();
  }

  float cv[2], ir[8];
#pragma unroll
  for (int y = 0; y < 2; ++y) cv[y] = colV[b * 512 + n0 + wn + y * 16 + fm];
#pragma unroll
  for (int x = 0; x < 2; ++x)
#pragma unroll
    for (int r = 0; r < 4; ++r)
      ir[x * 4 + r] = invR[b * 1024 + m0 + wm + x * 16 + fq * 4 + r];
  float* og = out + (long)b * (1024L * 512);
#pragma unroll
  for (int x = 0; x < 2; ++x)
#pragma unroll
    for (int y = 0; y < 2; ++y)
#pragma unroll
      for (int r = 0; r < 4; ++r) {
        int row = m0 + wm + x * 16 + fq * 4 + r;
        int col = n0 + wn + y * 16 + fm;
        og[(long)row * 512 + col] =
            (acc[x][y][r] + 1e-8f * cv[y]) * ir[x * 4 + r];
      }
}

extern "C" void kernel_launch(void* const* d_in, const int* in_sizes, int n_in,
                              void* d_out, int out_size, void* d_ws, size_t ws_size,
                              hipStream_t stream) {
  const float* inputs  = (const float*)d_in[0];
  const float* context = (const float*)d_in[1];
  const float* ln_in_g = (const float*)d_in[2];
  const float* ln_in_b = (const float*)d_in[3];
  const float* ln_ctx_g = (const float*)d_in[4];
  const float* ln_ctx_b = (const float*)d_in[5];
  const float* Wq = (const float*)d_in[6];
  const float* bq = (const float*)d_in[7];
  const float* Wk = (const float*)d_in[8];
  const float* bk = (const float*)d_in[9];
  const float* Wv = (const float*)d_in[10];
  const float* bv = (const float*)d_in[11];
  float* out = (float*)d_out;

  u16* ws = (u16*)d_ws;
  u16* xb  = ws;                        // [8192][512]
  u16* qb  = xb + 8192L * 512;          // [8192][512]
  u16* cb  = qb + 8192L * 512;          // [16384][512]
  u16* wqb = cb + 16384L * 512;         // [512][512]
  u16* wkb = wqb + 512L * 512;
  u16* wvb = wkb + 512L * 512;
  u16* kb  = wvb + 512L * 512;          // [16384][512]
  u16* vTs = kb + 16384L * 512;         // [8][512][2048] (v*rcp(Z), transposed)
  u16* E   = vTs + 8L * 512 * 2048;     // [8][1024][2048]
  float* Z    = (float*)(E + 8L * 1024 * 2048);   // [8][2048] raw col sums
  float* colV = Z + 8L * 2048;                    // [8][512]
  float* invR = colV + 8L * 512;                  // [8][1024]

  const float scale = 0.04419417382415922f;  // 512^-0.5

  // 1: LN(inputs)+LN(context) + weight cvt + zero Z/colV
  ln_prep<<<25364, 256, 0, stream>>>(inputs, ln_in_g, ln_in_b, xb,
                                     context, ln_ctx_g, ln_ctx_b, cb,
                                     Wq, Wk, Wv, wqb, wkb, wvb, Z);
  // 2: q-proj (bx<64) + k-proj (bx>=64), epi 0
  gemm_bt<<<dim3(192, 4, 1), 256, 0, stream>>>(xb, wqb, bq, qb,
      cb, wkb, bk, kb, 512, 0L, 0L, 0L, 512, 1.0f, 0, nullptr, nullptr);
  // 3: E = exp(q@k^T*scale), Z += col sums. epi 3, batch on blockIdx.x (XCD)
  gemm_bt<<<dim3(8, 16, 8), 256, 0, stream>>>(qb, kb, nullptr, E,
      nullptr, nullptr, nullptr, nullptr,
      512, 1024L * 512, 2048L * 512, 1024L * 2048, 2048, scale, 3, Z, nullptr);
  // 4: v-projT: vT[b][d][j] = (Wv[d]·cb[j] + bv[d])*rcp(Z), colV += row sums
  gemm_bt<<<dim3(4, 128, 1), 256, 0, stream>>>(wvb, cb, bv, vTs,
      nullptr, nullptr, nullptr, nullptr,
      512, 0L, 0L, 0L, 2048, 1.0f, 6, colV, Z);
  // 5: invR
  rowsumR<<<8192, 256, 0, stream>>>(E, Z, invR);
  // 6: PV direct, 64x64 tiles, 4 blocks/CU
  gemm_pv<<<dim3(16, 8, 8), 256, 0, stream>>>(E, vTs, colV, invR, out);
}

// Round 8
// 224.559 us; speedup vs baseline: 1.1917x; 1.0263x over previous
//
#include <hip/hip_runtime.h>

using u16 = unsigned short;
typedef __attribute__((ext_vector_type(8))) short short8;
typedef __attribute__((ext_vector_type(4))) float floatx4;

#define NQ 1024
#define NK 2048
#define DD 512

__device__ __forceinline__ u16 f2bf(float f) {
  union { float f; unsigned u; } x; x.f = f;
  unsigned r = (x.u + 0x7fffu + ((x.u >> 16) & 1u)) >> 16;
  return (u16)r;
}
__device__ __forceinline__ float bf2f(u16 u) {
  union { unsigned u; float f; } x; x.u = ((unsigned)u) << 16; return x.f;
}
__device__ __forceinline__ float wave_sum(float v) {
#pragma unroll
  for (int off = 32; off > 0; off >>= 1) v += __shfl_down(v, off, 64);
  return v;
}
__device__ __forceinline__ void gload16(const u16* g, const u16* l) {
  __builtin_amdgcn_global_load_lds(
      (const __attribute__((address_space(1))) void*)g,
      (__attribute__((address_space(3))) void*)l, 16, 0, 0);
}

// ------- fused: LN(inputs) + LN(context) + 3x weight cvt + zero Z/colV ------
__global__ __launch_bounds__(256) void ln_prep(
    const float* __restrict__ X1, const float* __restrict__ G1,
    const float* __restrict__ B1, u16* __restrict__ Y1,
    const float* __restrict__ X2, const float* __restrict__ G2,
    const float* __restrict__ B2, u16* __restrict__ Y2,
    const float* __restrict__ Wq, const float* __restrict__ Wk,
    const float* __restrict__ Wv, u16* __restrict__ wqb,
    u16* __restrict__ wkb, u16* __restrict__ wvb, float* __restrict__ Zero) {
  int row = blockIdx.x;
  const int t = threadIdx.x;
  if (row >= 24576) {
    int bx = row - 24576;
    if (bx < 768) {
      const float* src = bx < 256 ? Wq : (bx < 512 ? Wk : Wv);
      u16* dst = bx < 256 ? wqb : (bx < 512 ? wkb : wvb);
      int i = ((bx & 255) * 256 + t) * 4;
      float4 v = *(const float4*)(src + i);
      ushort4 o;
      o.x = f2bf(v.x); o.y = f2bf(v.y); o.z = f2bf(v.z); o.w = f2bf(v.w);
      *(ushort4*)(dst + i) = o;
    } else {
      int i = ((bx - 768) * 256 + t) * 4;
      float4 z = {0.f, 0.f, 0.f, 0.f};
      *(float4*)(Zero + i) = z;
    }
    return;
  }
  const float *X, *G, *Bv; u16* Y;
  if (row < 8192) { X = X1; G = G1; Bv = B1; Y = Y1; }
  else { row -= 8192; X = X2; G = G2; Bv = B2; Y = Y2; }
  const float2 v = ((const float2*)(X + (long)row * DD))[t];
  float s = v.x + v.y, ss = v.x * v.x + v.y * v.y;
  __shared__ float red[8];
  float a = wave_sum(s), b = wave_sum(ss);
  if ((t & 63) == 0) { red[t >> 6] = a; red[4 + (t >> 6)] = b; }
  __syncthreads();
  float tot = red[0] + red[1] + red[2] + red[3];
  float tss = red[4] + red[5] + red[6] + red[7];
  float mu = tot * (1.f / DD);
  float var = tss * (1.f / DD) - mu * mu;
  float rs = rsqrtf(var + 1e-5f);
  float2 g2 = ((const float2*)G)[t];
  float2 b2 = ((const float2*)Bv)[t];
  ushort2 o;
  o.x = f2bf((v.x - mu) * rs * g2.x + b2.x);
  o.y = f2bf((v.y - mu) * rs * g2.y + b2.y);
  ((ushort2*)(Y + (long)row * DD))[t] = o;
}

// ------------- GEMM (B^T form), BK=64, swizzled LDS: C = A·B^T --------------
// epi 0: bf16 out, C = val + bias[n]  (2nd problem at blockIdx.x>=64 if A2)
// epi 3: QK: batch = blockIdx.x, m0 = blockIdx.z*128.
//        bf16 E = exp(val*scale); col sums atomicAdd -> aux0 (Z)
// epi 6: v-projT: A=Wv, B=cb. bf16 vT[b][d][j] = (val+bias[d])*rcp(Z[b][j]);
//        row sums of unscaled val atomicAdd -> aux0 (colV[b][d])
__global__ __launch_bounds__(256) void gemm_bt(
    const u16* A, const u16* B, const float* bias, void* Cout,
    const u16* A2, const u16* B2, const float* bias2, void* Cout2,
    int K, long sAb, long sBb, long sCb, int ldC,
    float scale, int epi, float* aux0, const float* aux1) {
  __shared__ u16 lA[128 * 64];
  __shared__ u16 lB[128 * 64];
  __shared__ float colred[128];

  int m0, n0, bz;
  if (epi == 3) {
    bz = blockIdx.x; m0 = blockIdx.z * 128; n0 = blockIdx.y * 128;
  } else {
    bz = blockIdx.z; m0 = blockIdx.x * 128; n0 = blockIdx.y * 128;
    if (A2 != nullptr && blockIdx.x >= 64) {
      A = A2; B = B2; bias = bias2; Cout = Cout2;
      m0 = (blockIdx.x - 64) * 128;
    }
  }
  A += (long)bz * sAb;
  B += (long)bz * sBb;
  const int t = threadIdx.x, wave = t >> 6, lane = t & 63;
  const int fm = lane & 15, fq = lane >> 4;
  const int wm = (wave >> 1) * 64, wn = (wave & 1) * 64;

  const int srow = t >> 3;
  const int swz = ((t & 7) ^ (srow & 7)) * 8;
  const u16* gA = A + (long)(m0 + srow) * K + swz;
  const u16* gB = B + (long)(n0 + srow) * K + swz;
  const long gk32 = 32L * K;
  u16* dA = lA + wave * 512;
  u16* dB = lB + wave * 512;

  floatx4 acc[4][4];
#pragma unroll
  for (int x = 0; x < 4; ++x)
#pragma unroll
    for (int y = 0; y < 4; ++y) { floatx4 z = {0.f, 0.f, 0.f, 0.f}; acc[x][y] = z; }

  const int nkt = K >> 6;
  for (int kt = 0; kt < nkt; ++kt) {
    gload16(gA, dA);
    gload16(gA + gk32, dA + 2048);
    gload16(gA + 2 * gk32, dA + 4096);
    gload16(gA + 3 * gk32, dA + 6144);
    gload16(gB, dB);
    gload16(gB + gk32, dB + 2048);
    gload16(gB + 2 * gk32, dB + 4096);
    gload16(gB + 3 * gk32, dB + 6144);
    gA += 64; gB += 64;
    __syncthreads();
#pragma unroll
    for (int ks = 0; ks < 2; ++ks) {
      short8 af[4], bfr[4];
      const int csl = ((ks * 4 + fq) ^ (fm & 7)) * 8;
#pragma unroll
      for (int x = 0; x < 4; ++x)
        af[x] = *(const short8*)&lA[(wm + x * 16 + fm) * 64 + csl];
#pragma unroll
      for (int y = 0; y < 4; ++y)
        bfr[y] = *(const short8*)&lB[(wn + y * 16 + fm) * 64 + csl];
#pragma unroll
      for (int x = 0; x < 4; ++x)
#pragma unroll
        for (int y = 0; y < 4; ++y)
          acc[x][y] = __builtin_amdgcn_mfma_f32_16x16x32_bf16(af[x], bfr[y], acc[x][y], 0, 0, 0);
    }
    __syncthreads();
  }

  if (epi == 0) {
    float bs[4];
#pragma unroll
    for (int y = 0; y < 4; ++y) bs[y] = bias[n0 + wn + y * 16 + fm];
#pragma unroll
    for (int x = 0; x < 4; ++x)
#pragma unroll
      for (int y = 0; y < 4; ++y)
#pragma unroll
        for (int r = 0; r < 4; ++r) {
          int row = m0 + wm + x * 16 + fq * 4 + r;
          int col = n0 + wn + y * 16 + fm;
          ((u16*)Cout)[(long)bz * sCb + (long)row * ldC + col] =
              f2bf(acc[x][y][r] + bs[y]);
        }
  } else if (epi == 3) {
    float s4[4] = {0.f, 0.f, 0.f, 0.f};
#pragma unroll
    for (int x = 0; x < 4; ++x)
#pragma unroll
      for (int y = 0; y < 4; ++y)
#pragma unroll
        for (int r = 0; r < 4; ++r) {
          int row = m0 + wm + x * 16 + fq * 4 + r;
          int col = n0 + wn + y * 16 + fm;
          float e = __expf(acc[x][y][r] * scale);
          s4[y] += e;
          ((u16*)Cout)[(long)bz * sCb + (long)row * ldC + col] = f2bf(e);
        }
#pragma unroll
    for (int y = 0; y < 4; ++y) {
      s4[y] += __shfl_xor(s4[y], 16, 64);
      s4[y] += __shfl_xor(s4[y], 32, 64);
    }
    if (t < 128) colred[t] = 0.f;
    __syncthreads();
    if (fq == 0) {
#pragma unroll
      for (int y = 0; y < 4; ++y) atomicAdd(&colred[wn + y * 16 + fm], s4[y]);
    }
    __syncthreads();
    if (t < 128) atomicAdd(&aux0[bz * 2048 + n0 + t], colred[t]);
  } else {  // epi 6: v-projT
    const int bb = n0 >> 11;
    const int j0c = n0 & 2047;
    float bsr[4][4];
#pragma unroll
    for (int x = 0; x < 4; ++x)
#pragma unroll
      for (int r = 0; r < 4; ++r)
        bsr[x][r] = bias[m0 + wm + x * 16 + fq * 4 + r];
    float izv[4];
#pragma unroll
    for (int y = 0; y < 4; ++y)
      izv[y] = __builtin_amdgcn_rcpf(aux1[bb * 2048 + j0c + wn + y * 16 + fm]);
    u16* Cg = (u16*)Cout + (long)bb * (512L * 2048) + j0c;
    float rs[4][4];
#pragma unroll
    for (int x = 0; x < 4; ++x)
#pragma unroll
      for (int r = 0; r < 4; ++r) rs[x][r] = 0.f;
#pragma unroll
    for (int x = 0; x < 4; ++x)
#pragma unroll
      for (int y = 0; y < 4; ++y)
#pragma unroll
        for (int r = 0; r < 4; ++r) {
          int rowd = m0 + wm + x * 16 + fq * 4 + r;
          int col = wn + y * 16 + fm;
          float val = acc[x][y][r] + bsr[x][r];
          rs[x][r] += val;
          Cg[(long)rowd * 2048 + col] = f2bf(val * izv[y]);
        }
#pragma unroll
    for (int x = 0; x < 4; ++x)
#pragma unroll
      for (int r = 0; r < 4; ++r) {
        float s = rs[x][r];
        s += __shfl_xor(s, 1, 64);
        s += __shfl_xor(s, 2, 64);
        s += __shfl_xor(s, 4, 64);
        s += __shfl_xor(s, 8, 64);
        if (fm == 0)
          atomicAdd(&aux0[bb * 512 + m0 + wm + x * 16 + fq * 4 + r], s);
      }
  }
}

// ------- PV: out[b][i][d] = (sum_j E[i,j]*vT[d,j] + eps*colV[d]) * invR[i] --
// 64x64 tile, BK=64, grid (16,8,8)=1024. R[i] = sum_j E[i,j]*invZ[j] computed
// inline via an extra MFMA whose B-fragment is invZ (bf16, staged in LDS).
__global__ __launch_bounds__(256) void gemm_pv(const u16* __restrict__ E,
    const u16* __restrict__ V, const float* __restrict__ colV,
    const float* __restrict__ Z, float* __restrict__ out) {
  __shared__ u16 lA[64 * 64];
  __shared__ u16 lB[64 * 64];
  __shared__ u16 sZb[2048];
  const int b = blockIdx.z;
  const int m0 = blockIdx.x * 64, n0 = blockIdx.y * 64;
  const int t = threadIdx.x, wave = t >> 6, lane = t & 63;
  const int fm = lane & 15, fq = lane >> 4;
  const int wm = (wave >> 1) * 32, wn = (wave & 1) * 32;

  // stage invZ (bf16) once; visible after the first K-loop barrier
  {
    int i = t * 8;
    float4 z0 = *(const float4*)(Z + b * 2048 + i);
    float4 z1 = *(const float4*)(Z + b * 2048 + i + 4);
    short8 o;
    o[0] = (short)f2bf(__builtin_amdgcn_rcpf(z0.x));
    o[1] = (short)f2bf(__builtin_amdgcn_rcpf(z0.y));
    o[2] = (short)f2bf(__builtin_amdgcn_rcpf(z0.z));
    o[3] = (short)f2bf(__builtin_amdgcn_rcpf(z0.w));
    o[4] = (short)f2bf(__builtin_amdgcn_rcpf(z1.x));
    o[5] = (short)f2bf(__builtin_amdgcn_rcpf(z1.y));
    o[6] = (short)f2bf(__builtin_amdgcn_rcpf(z1.z));
    o[7] = (short)f2bf(__builtin_amdgcn_rcpf(z1.w));
    *(short8*)&sZb[i] = o;
  }

  const int srow = t >> 3;
  const int swz = ((t & 7) ^ (srow & 7)) * 8;
  const u16* gA = E + (long)b * (1024L * 2048) + (long)(m0 + srow) * 2048 + swz;
  const u16* gB = V + (long)b * (512L * 2048) + (long)(n0 + srow) * 2048 + swz;
  u16* dA = lA + wave * 512;
  u16* dB = lB + wave * 512;

  floatx4 acc[2][2];
  floatx4 accR[2];
#pragma unroll
  for (int x = 0; x < 2; ++x) {
    floatx4 z = {0.f, 0.f, 0.f, 0.f};
    accR[x] = z;
#pragma unroll
    for (int y = 0; y < 2; ++y) acc[x][y] = z;
  }

  for (int kt = 0; kt < 32; ++kt) {
    gload16(gA, dA);
    gload16(gA + 32L * 2048, dA + 2048);
    gload16(gB, dB);
    gload16(gB + 32L * 2048, dB + 2048);
    gA += 64; gB += 64;
    __syncthreads();
#pragma unroll
    for (int ks = 0; ks < 2; ++ks) {
      short8 af[2], bfr[2];
      const int chunk = ks * 4 + fq;
      const int csl = (chunk ^ (fm & 7)) * 8;
#pragma unroll
      for (int x = 0; x < 2; ++x)
        af[x] = *(const short8*)&lA[(wm + x * 16 + fm) * 64 + csl];
#pragma unroll
      for (int y = 0; y < 2; ++y)
        bfr[y] = *(const short8*)&lB[(wn + y * 16 + fm) * 64 + csl];
      short8 zf = *(const short8*)&sZb[kt * 64 + chunk * 8];
#pragma unroll
      for (int x = 0; x < 2; ++x) {
#pragma unroll
        for (int y = 0; y < 2; ++y)
          acc[x][y] = __builtin_amdgcn_mfma_f32_16x16x32_bf16(af[x], bfr[y], acc[x][y], 0, 0, 0);
        accR[x] = __builtin_amdgcn_mfma_f32_16x16x32_bf16(af[x], zf, accR[x], 0, 0, 0);
      }
    }
    __syncthreads();
  }

  float cv[2];
#pragma unroll
  for (int y = 0; y < 2; ++y) cv[y] = colV[b * 512 + n0 + wn + y * 16 + fm];
  float* og = out + (long)b * (1024L * 512);
#pragma unroll
  for (int x = 0; x < 2; ++x)
#pragma unroll
    for (int r = 0; r < 4; ++r) {
      float invR = __builtin_amdgcn_rcpf(accR[x][r] + 2048.f * 1e-8f);
      int row = m0 + wm + x * 16 + fq * 4 + r;
#pragma unroll
      for (int y = 0; y < 2; ++y) {
        int col = n0 + wn + y * 16 + fm;
        og[(long)row * 512 + col] = (acc[x][y][r] + 1e-8f * cv[y]) * invR;
      }
    }
}

extern "C" void kernel_launch(void* const* d_in, const int* in_sizes, int n_in,
                              void* d_out, int out_size, void* d_ws, size_t ws_size,
                              hipStream_t stream) {
  const float* inputs  = (const float*)d_in[0];
  const float* context = (const float*)d_in[1];
  const float* ln_in_g = (const float*)d_in[2];
  const float* ln_in_b = (const float*)d_in[3];
  const float* ln_ctx_g = (const float*)d_in[4];
  const float* ln_ctx_b = (const float*)d_in[5];
  const float* Wq = (const float*)d_in[6];
  const float* bq = (const float*)d_in[7];
  const float* Wk = (const float*)d_in[8];
  const float* bk = (const float*)d_in[9];
  const float* Wv = (const float*)d_in[10];
  const float* bv = (const float*)d_in[11];
  float* out = (float*)d_out;

  u16* ws = (u16*)d_ws;
  u16* xb  = ws;                        // [8192][512]
  u16* qb  = xb + 8192L * 512;          // [8192][512]
  u16* cb  = qb + 8192L * 512;          // [16384][512]
  u16* wqb = cb + 16384L * 512;         // [512][512]
  u16* wkb = wqb + 512L * 512;
  u16* wvb = wkb + 512L * 512;
  u16* kb  = wvb + 512L * 512;          // [16384][512]
  u16* vTs = kb + 16384L * 512;         // [8][512][2048] (v*rcp(Z), transposed)
  u16* E   = vTs + 8L * 512 * 2048;     // [8][1024][2048]
  float* Z    = (float*)(E + 8L * 1024 * 2048);   // [8][2048] raw col sums
  float* colV = Z + 8L * 2048;                    // [8][512]

  const float scale = 0.04419417382415922f;  // 512^-0.5

  // 1: LN(inputs)+LN(context) + weight cvt + zero Z/colV
  ln_prep<<<25364, 256, 0, stream>>>(inputs, ln_in_g, ln_in_b, xb,
                                     context, ln_ctx_g, ln_ctx_b, cb,
                                     Wq, Wk, Wv, wqb, wkb, wvb, Z);
  // 2: q-proj (bx<64) + k-proj (bx>=64), epi 0
  gemm_bt<<<dim3(192, 4, 1), 256, 0, stream>>>(xb, wqb, bq, qb,
      cb, wkb, bk, kb, 512, 0L, 0L, 0L, 512, 1.0f, 0, nullptr, nullptr);
  // 3: E = exp(q@k^T*scale), Z += col sums. epi 3, batch on blockIdx.x (XCD)
  gemm_bt<<<dim3(8, 16, 8), 256, 0, stream>>>(qb, kb, nullptr, E,
      nullptr, nullptr, nullptr, nullptr,
      512, 1024L * 512, 2048L * 512, 1024L * 2048, 2048, scale, 3, Z, nullptr);
  // 4: v-projT: vT[b][d][j] = (Wv[d]·cb[j] + bv[d])*rcp(Z), colV += row sums
  gemm_bt<<<dim3(4, 128, 1), 256, 0, stream>>>(wvb, cb, bv, vTs,
      nullptr, nullptr, nullptr, nullptr,
      512, 0L, 0L, 0L, 2048, 1.0f, 6, colV, Z);
  // 5: PV with inline R (extra MFMA vs staged invZ), direct epilogue
  gemm_pv<<<dim3(16, 8, 8), 256, 0, stream>>>(E, vTs, colV, Z, out);
}